// Round 4
// baseline (2777.828 us; speedup 1.0000x reference)
//
#include <hip/hip_runtime.h>
#include <cfloat>

#define N_ROWS 65536
#define DIM 256
#define K_CODES 2048

typedef float f32x2 __attribute__((ext_vector_type(2)));
typedef float f32x4 __attribute__((ext_vector_type(4)));
typedef short short8 __attribute__((ext_vector_type(8)));

// ---------------- bf16 helpers (RNE) ----------------
__device__ __forceinline__ unsigned short f2bf(float x) {
    unsigned u = __float_as_uint(x);
    u += 0x7fffu + ((u >> 16) & 1u);      // round-nearest-even
    return (unsigned short)(u >> 16);
}
__device__ __forceinline__ float bf2f(unsigned short b) {
    return __uint_as_float(((unsigned)b) << 16);
}

#define GLL16(gp, lp) \
    __builtin_amdgcn_global_load_lds((const __attribute__((address_space(1))) void*)(gp), \
                                     (__attribute__((address_space(3))) void*)(lp), 16, 0, 0)

// ---------------- e_sq precompute: one wave per code ----------------
__global__ __launch_bounds__(256)
void vq_esq_kernel(const float* __restrict__ emb, float* __restrict__ esq) {
    int w = threadIdx.x >> 6;
    int lane = threadIdx.x & 63;
    int k = blockIdx.x * 4 + w;
    float4 v = *(const float4*)&emb[(size_t)k * DIM + lane * 4];
    float s = v.x * v.x + v.y * v.y + v.z * v.z + v.w * v.w;
    #pragma unroll
    for (int off = 32; off >= 1; off >>= 1) s += __shfl_xor(s, off, 64);
    if (lane == 0) esq[k] = s;
}

// ---------------- z_sq precompute (replicates R2's reduction tree) ------
__global__ __launch_bounds__(256)
void vq_zsq_kernel(const float* __restrict__ z, float* __restrict__ zsq_g) {
    const int tid = threadIdx.x;
    const int m0 = blockIdx.x * 128;
    const int zr = tid >> 1, zh = tid & 1;
    const float* zp = &z[(size_t)(m0 + zr) * DIM + zh * 64];
    float sA = 0.f, sB = 0.f;
    #pragma unroll
    for (int d4 = 0; d4 < 16; ++d4) {
        float4 v = *(const float4*)&zp[d4 * 4];
        sA += v.x * v.x; sA += v.y * v.y; sA += v.z * v.z; sA += v.w * v.w;
    }
    #pragma unroll
    for (int d4 = 0; d4 < 16; ++d4) {
        float4 v = *(const float4*)&zp[128 + d4 * 4];
        sB += v.x * v.x; sB += v.y * v.y; sB += v.z * v.z; sB += v.w * v.w;
    }
    float s = sA + sB;
    s += __shfl_down(s, 1, 64);
    if (zh == 0) zsq_g[m0 + zr] = s;
}

// ---------------- exact 3-way bf16 split: x == h + m + l ----------------
__global__ __launch_bounds__(256)
void vq_split_kernel(const float* __restrict__ src,
                     unsigned short* __restrict__ H,
                     unsigned short* __restrict__ M,
                     unsigned short* __restrict__ L) {
    const size_t i = (size_t)blockIdx.x * 256 + threadIdx.x;
    float4 v = *(const float4*)&src[4 * i];
    ushort4 h, m, l;
    #define SPLIT1(c) { \
        h.c = f2bf(v.c); float hf = bf2f(h.c); float r = v.c - hf;   /* exact */ \
        m.c = f2bf(r);   float mf_ = bf2f(m.c); float r2 = r - mf_;  /* exact */ \
        l.c = f2bf(r2);  /* r2 has <=8 significant bits -> exact */ }
    SPLIT1(x) SPLIT1(y) SPLIT1(z) SPLIT1(w)
    #undef SPLIT1
    *(ushort4*)&H[4 * i] = h;
    *(ushort4*)&M[4 * i] = m;
    *(ushort4*)&L[4 * i] = l;
}

// ---------------- MFMA GEMM + approx top-2 argmin ----------------
// cross(z,e) = sum of 6 bf16 products (hh,hm,mh,hl,lh,mm) == fp32 cross to
// ~1e-10 rel (dropped ml,lm,ll) + fp32-accum rounding. K = 6*256 = 1536.
// Block: 128 rows x full 2048 codes (16 n-tiles), 256 thr / 4 waves (2x2),
// 64x64 per wave, 4x4 16x16x32 fragments. m97-style: global_load_lds(16B)
// double-buffered staging, one barrier per K-step.
// LDS swizzle: linear dest (gll requirement), source pre-swizzled
// chunk^=(row&3), frag reads apply same XOR -> ~2-way conflicts (free).
// Output: per row, top-2 (by (dist,idx) lexicographic) of EACH code-half
// -> 4 candidate indices; exact rescore happens in vq_rescue_kernel.
__global__ __launch_bounds__(256, 1)
void vq_gemm_kernel(const unsigned short* __restrict__ Zh,
                    const unsigned short* __restrict__ Zm,
                    const unsigned short* __restrict__ Zl,
                    const unsigned short* __restrict__ Eh,
                    const unsigned short* __restrict__ Em,
                    const unsigned short* __restrict__ El,
                    const float* __restrict__ zsq_g,
                    const float* __restrict__ esq_g,
                    int* __restrict__ top2) {
    __shared__ unsigned short ldsA[2][128 * 32];
    __shared__ unsigned short ldsB[2][128 * 32];
    __shared__ float zsq_s[128];

    const int tid  = threadIdx.x;
    const int m0   = blockIdx.x * 128;
    const int wid  = tid >> 6;
    const int lane = tid & 63;
    const int wm   = wid >> 1;                  // row half (0..1)
    const int wn   = wid & 1;                   // code half (0..1)
    const int srow = lane >> 2;                 // staging row in 16-row chunk
    const int schkG = (lane & 3) ^ (srow & 3);  // pre-swizzled source chunk

    if (tid < 128) zsq_s[tid] = zsq_g[m0 + tid];

    float b1v[16], b2v[16];
    int   b1i[16], b2i[16];
    #pragma unroll
    for (int r = 0; r < 16; ++r) {
        b1v[r] = FLT_MAX; b2v[r] = FLT_MAX;
        b1i[r] = 0x7fffffff; b2i[r] = 0x7fffffff;
    }

    // stage K-step (nt,kk) into buffer b: A 128x32 + B 128x32 bf16
    auto stage = [&](int nt, int kk, int b) {
        const int s  = kk >> 3;            // segment 0..5
        const int d0 = (kk & 7) * 32;      // d-offset within segment
        // segments: 0:(h,h) 1:(h,m) 2:(m,h) 3:(h,l) 4:(l,h) 5:(m,m)
        const unsigned short* Ap = (s == 4) ? Zl : ((s == 2 || s == 5) ? Zm : Zh);
        const unsigned short* Bp = (s == 3) ? El : ((s == 1 || s == 5) ? Em : Eh);
        #pragma unroll
        for (int i = 0; i < 2; ++i) {
            const int rr = wid * 32 + i * 16;
            const unsigned short* ga = Ap + (size_t)(m0 + rr + srow) * DIM + d0 + schkG * 8;
            GLL16(ga, &ldsA[b][rr * 32]);
            const unsigned short* gb = Bp + (size_t)(nt * 128 + rr + srow) * DIM + d0 + schkG * 8;
            GLL16(gb, &ldsB[b][rr * 32]);
        }
    };

    stage(0, 0, 0);
    __syncthreads();

    int p = 0;
    for (int nt = 0; nt < 16; ++nt) {
        f32x4 acc[4][4];
        #pragma unroll
        for (int a = 0; a < 4; ++a)
            #pragma unroll
            for (int bb = 0; bb < 4; ++bb)
                acc[a][bb] = (f32x4){0.f, 0.f, 0.f, 0.f};

        #pragma unroll 1
        for (int kk = 0; kk < 48; ++kk) {
            // prefetch next step (clamped dummy at the very end)
            int kn = kk + 1, ntn = nt;
            if (kn == 48) { kn = 0; ntn = nt + 1; if (ntn == 16) { ntn = 15; kn = 47; } }
            stage(ntn, kn, p ^ 1);

            const int kc = lane >> 4;
            short8 aF[4], bF[4];
            #pragma unroll
            for (int mf = 0; mf < 4; ++mf) {
                const int row = wm * 64 + mf * 16 + (lane & 15);
                aF[mf] = *(const short8*)((const char*)&ldsA[p][0] + row * 64 + ((kc ^ (row & 3)) << 4));
            }
            #pragma unroll
            for (int nf = 0; nf < 4; ++nf) {
                const int row = wn * 64 + nf * 16 + (lane & 15);
                bF[nf] = *(const short8*)((const char*)&ldsB[p][0] + row * 64 + ((kc ^ (row & 3)) << 4));
            }
            #pragma unroll
            for (int mf = 0; mf < 4; ++mf)
                #pragma unroll
                for (int nf = 0; nf < 4; ++nf)
                    acc[mf][nf] = __builtin_amdgcn_mfma_f32_16x16x32_bf16(aF[mf], bF[nf], acc[mf][nf], 0, 0, 0);

            __syncthreads();
            p ^= 1;
        }

        // ---- score this n-tile: dist = fl(zs+es) - 2*cross, update top2 ----
        float zsv[16];
        #pragma unroll
        for (int mf = 0; mf < 4; ++mf)
            #pragma unroll
            for (int rg = 0; rg < 4; ++rg)
                zsv[mf * 4 + rg] = zsq_s[wm * 64 + mf * 16 + (lane >> 4) * 4 + rg];
        #pragma unroll
        for (int nf = 0; nf < 4; ++nf) {
            const int code = nt * 128 + wn * 64 + nf * 16 + (lane & 15);
            const float es = esq_g[code];
            #pragma unroll
            for (int mf = 0; mf < 4; ++mf) {
                #pragma unroll
                for (int rg = 0; rg < 4; ++rg) {
                    const int r = mf * 4 + rg;
                    float t = zsv[r] + es;
                    float dist = t - 2.0f * acc[mf][nf][rg];
                    bool better1 = (dist < b1v[r]) || (dist == b1v[r] && code < b1i[r]);
                    float ob1v = b1v[r]; int ob1i = b1i[r];
                    if (better1) { b1v[r] = dist; b1i[r] = code; }
                    float dv = better1 ? ob1v : dist;
                    int   di = better1 ? ob1i : code;
                    bool ins2 = (dv < b2v[r]) || (dv == b2v[r] && di < b2i[r]);
                    if (ins2) { b2v[r] = dv; b2i[r] = di; }
                }
            }
        }
    }

    // ---- cross-lane top2 merge over the 16 code-columns ----
    #pragma unroll
    for (int r = 0; r < 16; ++r) {
        #pragma unroll
        for (int off = 1; off <= 8; off <<= 1) {
            float o1v = __shfl_xor(b1v[r], off, 64); int o1i = __shfl_xor(b1i[r], off, 64);
            float o2v = __shfl_xor(b2v[r], off, 64); int o2i = __shfl_xor(b2i[r], off, 64);
            bool t1 = (o1v < b1v[r]) || (o1v == b1v[r] && o1i < b1i[r]);
            float dv = t1 ? b1v[r] : o1v; int di = t1 ? b1i[r] : o1i;
            if (t1) { b1v[r] = o1v; b1i[r] = o1i; }
            bool t2 = (dv < b2v[r]) || (dv == b2v[r] && di < b2i[r]);
            if (t2) { b2v[r] = dv; b2i[r] = di; }
            bool t3 = (o2v < b2v[r]) || (o2v == b2v[r] && o2i < b2i[r]);
            if (t3) { b2v[r] = o2v; b2i[r] = o2i; }
        }
    }
    if ((lane & 15) == 0) {
        #pragma unroll
        for (int r = 0; r < 16; ++r) {
            const int rowg = m0 + wm * 64 + (r >> 2) * 16 + (lane >> 4) * 4 + (r & 3);
            top2[rowg * 4 + wn * 2 + 0] = b1i[r];
            top2[rowg * 4 + wn * 2 + 1] = b2i[r];
        }
    }
}

// ---------------- exact rescore of 4 candidates + epilogue ----------------
// Lanes 0..3 of each 4-group compute the exact fp32 distance chain
// (d ascending, fmaf, same zsq/esq values) for one candidate; lexicographic
// min over the group == exact argmin provided true winner is in the 4.
__global__ __launch_bounds__(256)
void vq_rescue_kernel(const float* __restrict__ z, const float* __restrict__ emb,
                      const float* __restrict__ zsq_g, const float* __restrict__ esq_g,
                      const int* __restrict__ top2,
                      float* __restrict__ out, float* __restrict__ loss_acc) {
    __shared__ float lred[4];
    const int tid = threadIdx.x;
    const int wid = tid >> 6, lane = tid & 63;
    const int row = blockIdx.x * 4 + wid;
    const int cand = top2[row * 4 + (lane & 3)];
    const float* zr = z + (size_t)row * DIM;
    const float* er = emb + (size_t)cand * DIM;
    float a = 0.f;
    #pragma unroll 8
    for (int d4 = 0; d4 < 64; ++d4) {
        float4 zv = *(const float4*)&zr[4 * d4];
        float4 ev = *(const float4*)&er[4 * d4];
        a = fmaf(zv.x, ev.x, a); a = fmaf(zv.y, ev.y, a);
        a = fmaf(zv.z, ev.z, a); a = fmaf(zv.w, ev.w, a);
    }
    float t = zsq_g[row] + esq_g[cand];
    float dist = t - 2.0f * a;
    int best = cand;
    #pragma unroll
    for (int off = 1; off <= 2; off <<= 1) {
        float ov = __shfl_xor(dist, off, 64);
        int   oi = __shfl_xor(best, off, 64);
        bool tk = (ov < dist) || (ov == dist && oi < best);
        dist = tk ? ov : dist; best = tk ? oi : best;
    }
    // epilogue: z_q_st, loss partial, index
    float4 q4 = *(const float4*)&emb[(size_t)best * DIM + 4 * lane];
    float4 z4 = *(const float4*)&zr[4 * lane];
    float4 o; float dx, lsum = 0.f;
    dx = q4.x - z4.x; o.x = z4.x + dx; lsum = fmaf(dx, dx, lsum);
    dx = q4.y - z4.y; o.y = z4.y + dx; lsum = fmaf(dx, dx, lsum);
    dx = q4.z - z4.z; o.z = z4.z + dx; lsum = fmaf(dx, dx, lsum);
    dx = q4.w - z4.w; o.w = z4.w + dx; lsum = fmaf(dx, dx, lsum);
    *(float4*)&out[(size_t)row * DIM + 4 * lane] = o;
    #pragma unroll
    for (int off = 32; off >= 1; off >>= 1) lsum += __shfl_xor(lsum, off, 64);
    if (lane == 0) lred[wid] = lsum;
    __syncthreads();
    if (tid == 0) atomicAdd(loss_acc, lred[0] + lred[1] + lred[2] + lred[3]);
    if (lane == 0) out[(size_t)N_ROWS * DIM + 1 + row] = (float)best;
}

// =================== legacy R2 path (fallback if ws too small) ===========
#define MT 128
#define KT 256
#define DC 16
#define BLOCK 256
#define ZSTR (MT + 4)
#define ESTR (KT + 4)
#define NSTAGES ((DIM / DC) * (K_CODES / KT))

#define LOHALF(v) __builtin_shufflevector(v, v, 0, 1)
#define HIHALF(v) __builtin_shufflevector(v, v, 2, 3)
#define PK_FMA_LO(acc, ap, bp) \
    asm("v_pk_fma_f32 %0, %1, %2, %0 op_sel:[0,0,0] op_sel_hi:[0,1,1]" \
        : "+v"(acc) : "v"(ap), "v"(bp))
#define PK_FMA_HI(acc, ap, bp) \
    asm("v_pk_fma_f32 %0, %1, %2, %0 op_sel:[1,0,0] op_sel_hi:[1,1,1]" \
        : "+v"(acc) : "v"(ap), "v"(bp))

__global__ __launch_bounds__(BLOCK, 1)
void vq_main_kernel(const float* __restrict__ z,
                    const float* __restrict__ emb,
                    const float* __restrict__ esq,
                    float* __restrict__ out,
                    float* __restrict__ loss_acc) {
    __shared__ float zS[2][DC][ZSTR];
    __shared__ float eT[2][DC][ESTR];
    __shared__ float zsq_s[MT];
    __shared__ int   best_s[MT];
    __shared__ float lred[4];

    const int tid = threadIdx.x;
    const int m0  = blockIdx.x * MT;
    const int rg  = tid >> 5;
    const int cg  = tid & 31;
    const int esr = tid >> 2;
    const int esf = tid & 3;
    const int zr  = tid >> 1;
    const int zh  = tid & 1;

    {
        const float* zp = &z[(size_t)(m0 + zr) * DIM + zh * 64];
        float sA = 0.f, sB = 0.f;
        #pragma unroll
        for (int d4 = 0; d4 < 16; ++d4) {
            float4 v = *(const float4*)&zp[d4 * 4];
            sA += v.x * v.x; sA += v.y * v.y; sA += v.z * v.z; sA += v.w * v.w;
        }
        #pragma unroll
        for (int d4 = 0; d4 < 16; ++d4) {
            float4 v = *(const float4*)&zp[128 + d4 * 4];
            sB += v.x * v.x; sB += v.y * v.y; sB += v.z * v.z; sB += v.w * v.w;
        }
        float s = sA + sB;
        s += __shfl_down(s, 1, 64);
        if (zh == 0) zsq_s[zr] = s;
    }
    {
        const float* zp = &z[(size_t)(m0 + zr) * DIM + 8 * zh];
        float4 za = *(const float4*)&zp[0];
        float4 zb = *(const float4*)&zp[4];
        zS[0][8 * zh + 0][zr] = za.x; zS[0][8 * zh + 1][zr] = za.y;
        zS[0][8 * zh + 2][zr] = za.z; zS[0][8 * zh + 3][zr] = za.w;
        zS[0][8 * zh + 4][zr] = zb.x; zS[0][8 * zh + 5][zr] = zb.y;
        zS[0][8 * zh + 6][zr] = zb.z; zS[0][8 * zh + 7][zr] = zb.w;
        #pragma unroll
        for (int cb = 0; cb < 4; ++cb) {
            int c = esr + cb * 64;
            float4 ev = *(const float4*)&emb[(size_t)c * DIM + 4 * esf];
            eT[0][4 * esf + 0][c] = ev.x; eT[0][4 * esf + 1][c] = ev.y;
            eT[0][4 * esf + 2][c] = ev.z; eT[0][4 * esf + 3][c] = ev.w;
        }
    }
    __syncthreads();

    float bestv[16];
    int   besti[16];
    #pragma unroll
    for (int j = 0; j < 16; ++j) { bestv[j] = FLT_MAX; besti[j] = 0; }

    f32x2 acc2[16][4];

    for (int s = 0; s < NSTAGES; ++s) {
        const int p     = s & 1;
        const int kt    = (s >> 4) * KT;
        const int dcIdx = s & 15;

        if (dcIdx == 0) {
            #pragma unroll
            for (int j = 0; j < 16; ++j)
                #pragma unroll
                for (int i2 = 0; i2 < 4; ++i2) acc2[j][i2] = (f32x2){0.f, 0.f};
        }

        const int sn  = (s + 1 < NSTAGES) ? s + 1 : s;
        const int nkt = (sn >> 4) * KT;
        const int ndc = (sn & 15) * DC;
        float4 zn0 = *(const float4*)&z[(size_t)(m0 + zr) * DIM + ndc + 8 * zh];
        float4 zn1 = *(const float4*)&z[(size_t)(m0 + zr) * DIM + ndc + 8 * zh + 4];
        float4 en0 = *(const float4*)&emb[(size_t)(nkt + esr +   0) * DIM + ndc + 4 * esf];
        float4 en1 = *(const float4*)&emb[(size_t)(nkt + esr +  64) * DIM + ndc + 4 * esf];
        float4 en2 = *(const float4*)&emb[(size_t)(nkt + esr + 128) * DIM + ndc + 4 * esf];
        float4 en3 = *(const float4*)&emb[(size_t)(nkt + esr + 192) * DIM + ndc + 4 * esf];

        #pragma unroll
        for (int d = 0; d < DC; ++d) {
            f32x4 a0 = *(const f32x4*)&zS[p][d][16 * rg];
            f32x4 a1 = *(const f32x4*)&zS[p][d][16 * rg + 4];
            f32x4 a2 = *(const f32x4*)&zS[p][d][16 * rg + 8];
            f32x4 a3 = *(const f32x4*)&zS[p][d][16 * rg + 12];
            f32x4 b0 = *(const f32x4*)&eT[p][d][4 * cg];
            f32x4 b1 = *(const f32x4*)&eT[p][d][128 + 4 * cg];
            f32x2 ap[8] = { LOHALF(a0), HIHALF(a0), LOHALF(a1), HIHALF(a1),
                            LOHALF(a2), HIHALF(a2), LOHALF(a3), HIHALF(a3) };
            f32x2 bp[4] = { LOHALF(b0), HIHALF(b0), LOHALF(b1), HIHALF(b1) };
            #pragma unroll
            for (int jp = 0; jp < 8; ++jp) {
                #pragma unroll
                for (int i2 = 0; i2 < 4; ++i2) {
                    PK_FMA_LO(acc2[2 * jp][i2],     ap[jp], bp[i2]);
                    PK_FMA_HI(acc2[2 * jp + 1][i2], ap[jp], bp[i2]);
                }
            }
        }
        {
            const int q = p ^ 1;
            zS[q][8 * zh + 0][zr] = zn0.x; zS[q][8 * zh + 1][zr] = zn0.y;
            zS[q][8 * zh + 2][zr] = zn0.z; zS[q][8 * zh + 3][zr] = zn0.w;
            zS[q][8 * zh + 4][zr] = zn1.x; zS[q][8 * zh + 5][zr] = zn1.y;
            zS[q][8 * zh + 6][zr] = zn1.z; zS[q][8 * zh + 7][zr] = zn1.w;
            eT[q][4 * esf + 0][esr      ] = en0.x; eT[q][4 * esf + 1][esr      ] = en0.y;
            eT[q][4 * esf + 2][esr      ] = en0.z; eT[q][4 * esf + 3][esr      ] = en0.w;
            eT[q][4 * esf + 0][esr +  64] = en1.x; eT[q][4 * esf + 1][esr +  64] = en1.y;
            eT[q][4 * esf + 2][esr +  64] = en1.z; eT[q][4 * esf + 3][esr +  64] = en1.w;
            eT[q][4 * esf + 0][esr + 128] = en2.x; eT[q][4 * esf + 1][esr + 128] = en2.y;
            eT[q][4 * esf + 2][esr + 128] = en2.z; eT[q][4 * esf + 3][esr + 128] = en2.w;
            eT[q][4 * esf + 0][esr + 192] = en3.x; eT[q][4 * esf + 1][esr + 192] = en3.y;
            eT[q][4 * esf + 2][esr + 192] = en3.z; eT[q][4 * esf + 3][esr + 192] = en3.w;
        }
        if (dcIdx == 15) {
            float4 e0 = *(const float4*)&esq[kt + 4 * cg];
            float4 e1 = *(const float4*)&esq[kt + 128 + 4 * cg];
            float es[8] = {e0.x, e0.y, e0.z, e0.w, e1.x, e1.y, e1.z, e1.w};
            #pragma unroll
            for (int j = 0; j < 16; ++j) {
                float zs = zsq_s[16 * rg + j];
                #pragma unroll
                for (int i = 0; i < 8; ++i) {
                    float aij  = acc2[j][i >> 1][i & 1];
                    float t    = zs + es[i];
                    float dist = t - 2.0f * aij;
                    int idx = (i < 4) ? (kt + 4 * cg + i) : (kt + 128 + 4 * cg + (i - 4));
                    bool better = (dist < bestv[j]);
                    bestv[j] = better ? dist : bestv[j];
                    besti[j] = better ? idx  : besti[j];
                }
            }
        }
        __syncthreads();
    }

    #pragma unroll
    for (int off = 16; off >= 1; off >>= 1) {
        #pragma unroll
        for (int j = 0; j < 16; ++j) {
            float ov = __shfl_xor(bestv[j], off, 64);
            int   oi = __shfl_xor(besti[j], off, 64);
            bool take = (ov < bestv[j]) || (ov == bestv[j] && oi < besti[j]);
            bestv[j] = take ? ov : bestv[j];
            besti[j] = take ? oi : besti[j];
        }
    }
    if (cg == 0) {
        #pragma unroll
        for (int j = 0; j < 16; ++j) best_s[16 * rg + j] = besti[j];
    }
    __syncthreads();

    float lsum = 0.f;
    const int d4 = tid & 63;
    for (int it = 0; it < 32; ++it) {
        int r  = (tid >> 6) + it * 4;
        int bk = best_s[r];
        float4 q4 = *(const float4*)&emb[(size_t)bk * DIM + 4 * d4];
        float4 z4 = *(const float4*)&z[(size_t)(m0 + r) * DIM + 4 * d4];
        float4 o;
        float dx;
        dx = q4.x - z4.x; o.x = z4.x + dx; lsum = fmaf(dx, dx, lsum);
        dx = q4.y - z4.y; o.y = z4.y + dx; lsum = fmaf(dx, dx, lsum);
        dx = q4.z - z4.z; o.z = z4.z + dx; lsum = fmaf(dx, dx, lsum);
        dx = q4.w - z4.w; o.w = z4.w + dx; lsum = fmaf(dx, dx, lsum);
        *(float4*)&out[(size_t)(m0 + r) * DIM + 4 * d4] = o;
    }
    #pragma unroll
    for (int off = 32; off >= 1; off >>= 1) lsum += __shfl_xor(lsum, off, 64);
    if ((tid & 63) == 0) lred[tid >> 6] = lsum;
    __syncthreads();
    if (tid == 0) {
        float bs = lred[0] + lred[1] + lred[2] + lred[3];
        atomicAdd(loss_acc, bs);
    }
    if (tid < MT) out[(size_t)N_ROWS * DIM + 1 + m0 + tid] = (float)best_s[tid];
}

// ---------------- finalize: vq_loss = 1.25 * mean ----------------
__global__ void vq_finalize_kernel(const float* __restrict__ loss_acc,
                                   float* __restrict__ out) {
    double s = (double)loss_acc[0];
    out[(size_t)N_ROWS * DIM] = (float)(s * 1.25 / ((double)N_ROWS * (double)DIM));
}

extern "C" void kernel_launch(void* const* d_in, const int* in_sizes, int n_in,
                              void* d_out, int out_size, void* d_ws, size_t ws_size,
                              hipStream_t stream) {
    (void)in_sizes; (void)n_in; (void)out_size;
    const float* z   = (const float*)d_in[0];
    const float* emb = (const float*)d_in[1];
    float* out = (float*)d_out;
    char* wsb = (char*)d_ws;
    float* loss_acc = (float*)wsb;              // @0
    float* esq      = (float*)(wsb + 1024);     // 2048 f

    hipMemsetAsync(d_ws, 0, sizeof(float), stream);
    vq_esq_kernel<<<K_CODES / 4, 256, 0, stream>>>(emb, esq);

    const size_t NEED = (size_t)104 << 20;      // Zh/Zm/Zl end at 104 MiB
    if (ws_size >= NEED) {
        float* zsq_g = (float*)(wsb + 16384);              // 65536 f
        int*   top2  = (int*)(wsb + ((size_t)1 << 19));    // 65536*4 int
        unsigned short* Eh = (unsigned short*)(wsb + ((size_t)2 << 20));
        unsigned short* Em = (unsigned short*)(wsb + ((size_t)3 << 20));
        unsigned short* El = (unsigned short*)(wsb + ((size_t)4 << 20));
        unsigned short* Zh = (unsigned short*)(wsb + ((size_t)8 << 20));
        unsigned short* Zm = (unsigned short*)(wsb + ((size_t)40 << 20));
        unsigned short* Zl = (unsigned short*)(wsb + ((size_t)72 << 20));
        vq_zsq_kernel<<<N_ROWS / 128, 256, 0, stream>>>(z, zsq_g);
        vq_split_kernel<<<(N_ROWS * DIM) / 1024, 256, 0, stream>>>(z, Zh, Zm, Zl);
        vq_split_kernel<<<(K_CODES * DIM) / 1024, 256, 0, stream>>>(emb, Eh, Em, El);
        vq_gemm_kernel<<<N_ROWS / 128, 256, 0, stream>>>(Zh, Zm, Zl, Eh, Em, El,
                                                         zsq_g, esq, top2);
        vq_rescue_kernel<<<N_ROWS / 4, 256, 0, stream>>>(z, emb, zsq_g, esq, top2,
                                                         out, loss_acc);
    } else {
        vq_main_kernel<<<N_ROWS / MT, BLOCK, 0, stream>>>(z, emb, esq, out, loss_acc);
    }
    vq_finalize_kernel<<<1, 1, 0, stream>>>(loss_acc, out);
}

// Round 5
// 1289.819 us; speedup vs baseline: 2.1537x; 2.1537x over previous
//
#include <hip/hip_runtime.h>
#include <cfloat>

#define N_ROWS 65536
#define DIM 256
#define K_CODES 2048

typedef float f32x2 __attribute__((ext_vector_type(2)));
typedef float f32x4 __attribute__((ext_vector_type(4)));
typedef short short8 __attribute__((ext_vector_type(8)));

// ---------------- bf16 helpers (RNE) ----------------
__device__ __forceinline__ unsigned short f2bf(float x) {
    unsigned u = __float_as_uint(x);
    u += 0x7fffu + ((u >> 16) & 1u);      // round-nearest-even
    return (unsigned short)(u >> 16);
}
__device__ __forceinline__ float bf2f(unsigned short b) {
    return __uint_as_float(((unsigned)b) << 16);
}

#define GLL16(gp, lp) \
    __builtin_amdgcn_global_load_lds((const __attribute__((address_space(1))) void*)(gp), \
                                     (__attribute__((address_space(3))) void*)(lp), 16, 0, 0)

// ---------------- e_sq precompute: one wave per code ----------------
__global__ __launch_bounds__(256)
void vq_esq_kernel(const float* __restrict__ emb, float* __restrict__ esq) {
    int w = threadIdx.x >> 6;
    int lane = threadIdx.x & 63;
    int k = blockIdx.x * 4 + w;
    float4 v = *(const float4*)&emb[(size_t)k * DIM + lane * 4];
    float s = v.x * v.x + v.y * v.y + v.z * v.z + v.w * v.w;
    #pragma unroll
    for (int off = 32; off >= 1; off >>= 1) s += __shfl_xor(s, off, 64);
    if (lane == 0) esq[k] = s;
}

// ---------------- z_sq precompute (replicates R2's reduction tree) ------
__global__ __launch_bounds__(256)
void vq_zsq_kernel(const float* __restrict__ z, float* __restrict__ zsq_g) {
    const int tid = threadIdx.x;
    const int m0 = blockIdx.x * 128;
    const int zr = tid >> 1, zh = tid & 1;
    const float* zp = &z[(size_t)(m0 + zr) * DIM + zh * 64];
    float sA = 0.f, sB = 0.f;
    #pragma unroll
    for (int d4 = 0; d4 < 16; ++d4) {
        float4 v = *(const float4*)&zp[d4 * 4];
        sA += v.x * v.x; sA += v.y * v.y; sA += v.z * v.z; sA += v.w * v.w;
    }
    #pragma unroll
    for (int d4 = 0; d4 < 16; ++d4) {
        float4 v = *(const float4*)&zp[128 + d4 * 4];
        sB += v.x * v.x; sB += v.y * v.y; sB += v.z * v.z; sB += v.w * v.w;
    }
    float s = sA + sB;
    s += __shfl_down(s, 1, 64);
    if (zh == 0) zsq_g[m0 + zr] = s;
}

// ---------------- 2-way bf16 split: x ~= h + m (drop the l plane) -------
__global__ __launch_bounds__(256)
void vq_split2_kernel(const float* __restrict__ src,
                      unsigned short* __restrict__ H,
                      unsigned short* __restrict__ M) {
    const size_t i = (size_t)blockIdx.x * 256 + threadIdx.x;
    float4 v = *(const float4*)&src[4 * i];
    ushort4 h, m;
    #define SP1(c) { h.c = f2bf(v.c); float r = v.c - bf2f(h.c); m.c = f2bf(r); }
    SP1(x) SP1(y) SP1(z) SP1(w)
    #undef SP1
    *(ushort4*)&H[4 * i] = h;
    *(ushort4*)&M[4 * i] = m;
}

// ---------------- MFMA GEMM v2: A-resident, 3 segments ----------------
// cross ~= hh + hm + mh (error ~4e-8 abs; selection fixed by exact rescue).
// Block: 64 rows x 2048 codes. A = 64 rows x {Zh,Zm} x 256d = 64 KB LDS,
// staged ONCE (kills the x16 A-restage that made R3 HBM-bound).
// B streamed per nt (256 codes) in 8 BK=64 tiles: s=0..3 Eh (feeds segs
// hh AND mh -> 64 MFMA/barrier), s=4..7 Em (seg hm -> 32 MFMA/barrier).
// Swizzle: 128B rows, slot = chunk ^ (row&7) -> 8 bank-starts x2 = free.
// GLL16: linear LDS dest, pre-swizzled global source (same involution).
// Output: top-2 per code-half per row -> exact rescore in vq_rescue_kernel.
__global__ __launch_bounds__(256, 1)
void vq_gemm_kernel(const unsigned short* __restrict__ Zh,
                    const unsigned short* __restrict__ Zm,
                    const unsigned short* __restrict__ Eh,
                    const unsigned short* __restrict__ Em,
                    const float* __restrict__ zsq_g,
                    const float* __restrict__ esq_g,
                    int* __restrict__ top2) {
    __shared__ __align__(16) unsigned short Albs[8 * 64 * 64];   // 64 KB
    __shared__ __align__(16) unsigned short Bbuf[2 * 256 * 64];  // 64 KB
    __shared__ float zsq_s[64];
    __shared__ float mv[2][4][64][2];
    __shared__ int   mi[2][4][64][2];

    const int tid  = threadIdx.x;
    const int wid  = tid >> 6;
    const int lane = tid & 63;
    const int m0   = blockIdx.x * 64;
    const int rowL = lane & 15;
    const int kc   = lane >> 4;

    if (tid < 64) zsq_s[tid] = zsq_g[m0 + tid];

    // ---- persistent A stage: regions 0-3 = Zh kkb 0-3, 4-7 = Zm kkb 0-3 ----
    {
        const int slot = lane & 7;
        #pragma unroll
        for (int i = 0; i < 16; ++i) {
            const int rowlin = wid * 128 + i * 8 + (lane >> 3);  // 0..511
            const int region = rowlin >> 6;
            const int r      = rowlin & 63;
            const int c      = slot ^ (r & 7);
            const unsigned short* Ap = (region < 4) ? Zh : Zm;
            const int kkb = region & 3;
            GLL16(Ap + (size_t)(m0 + r) * DIM + kkb * 64 + c * 8,
                  (char*)Albs + wid * 16384 + i * 1024);
        }
    }

    // ---- B tile stage: 256 codes x 64 d, each wave stages its 64 codes ----
    auto stage_b = [&](int nt_, int s_, int buf_) {
        const unsigned short* Bp = (s_ < 4) ? Eh : Em;
        const int kkb  = s_ & 3;
        const int slot = lane & 7;
        #pragma unroll
        for (int i = 0; i < 8; ++i) {
            const int codelin = wid * 64 + i * 8 + (lane >> 3);
            const int c = slot ^ (codelin & 7);
            GLL16(Bp + (size_t)(nt_ * 256 + codelin) * DIM + kkb * 64 + c * 8,
                  (char*)Bbuf + buf_ * 32768 + wid * 8192 + i * 1024);
        }
    };

    stage_b(0, 0, 0);
    __syncthreads();

    float b1v[16], b2v[16];
    int   b1i[16], b2i[16];
    #pragma unroll
    for (int e = 0; e < 16; ++e) {
        b1v[e] = FLT_MAX; b2v[e] = FLT_MAX;
        b1i[e] = 0x7fffffff; b2i[e] = 0x7fffffff;
    }

    #pragma unroll 1
    for (int nt = 0; nt < 8; ++nt) {
        f32x4 acc[4][4];
        #pragma unroll
        for (int mf = 0; mf < 4; ++mf)
            #pragma unroll
            for (int nf = 0; nf < 4; ++nf)
                acc[mf][nf] = (f32x4){0.f, 0.f, 0.f, 0.f};

        #pragma unroll
        for (int s = 0; s < 8; ++s) {
            const int cb = s & 1;    // compute buffer (s-loop fully unrolled)
            // prefetch next tile into the other buffer
            {
                const int sn  = (s + 1) & 7;
                const int ntn = (s == 7) ? nt + 1 : nt;
                if (ntn < 8) stage_b(ntn, sn, cb ^ 1);
            }
            // B fragments for this tile
            short8 bF[4][2];
            #pragma unroll
            for (int nf = 0; nf < 4; ++nf)
                #pragma unroll
                for (int kh = 0; kh < 2; ++kh) {
                    const int code = wid * 64 + nf * 16 + rowL;
                    const int sw = (kh * 4 + kc) ^ (code & 7);
                    bF[nf][kh] = *(const short8*)((const char*)Bbuf + cb * 32768 + code * 128 + sw * 16);
                }
            // A-plane passes: s<4 (Eh): Zh then Zm; s>=4 (Em): Zh only
            const int NPL = (s < 4) ? 2 : 1;
            #pragma unroll
            for (int pl = 0; pl < NPL; ++pl) {
                const int region = (pl == 0 ? 0 : 4) + (s & 3);
                short8 aF[4][2];
                #pragma unroll
                for (int mf = 0; mf < 4; ++mf)
                    #pragma unroll
                    for (int kh = 0; kh < 2; ++kh) {
                        const int r = mf * 16 + rowL;
                        const int sw = (kh * 4 + kc) ^ (r & 7);
                        aF[mf][kh] = *(const short8*)((const char*)Albs + region * 8192 + r * 128 + sw * 16);
                    }
                #pragma unroll
                for (int kh = 0; kh < 2; ++kh)
                    #pragma unroll
                    for (int mf = 0; mf < 4; ++mf)
                        #pragma unroll
                        for (int nf = 0; nf < 4; ++nf)
                            acc[mf][nf] = __builtin_amdgcn_mfma_f32_16x16x32_bf16(
                                aF[mf][kh], bF[nf][kh], acc[mf][nf], 0, 0, 0);
            }
            __syncthreads();
        }

        // ---- score this nt: dist = fl(zs+es) - 2*cross, running top-2 ----
        #pragma unroll
        for (int nf = 0; nf < 4; ++nf) {
            const int code = nt * 256 + wid * 64 + nf * 16 + rowL;
            const float es = esq_g[code];
            #pragma unroll
            for (int mf = 0; mf < 4; ++mf)
                #pragma unroll
                for (int rg = 0; rg < 4; ++rg) {
                    const int e = mf * 4 + rg;
                    const float zs = zsq_s[mf * 16 + (lane >> 4) * 4 + rg];
                    float t = zs + es;
                    float dist = t - 2.0f * acc[mf][nf][rg];
                    bool better1 = (dist < b1v[e]) || (dist == b1v[e] && code < b1i[e]);
                    float ov = b1v[e]; int oi = b1i[e];
                    if (better1) { b1v[e] = dist; b1i[e] = code; }
                    float dv = better1 ? ov : dist;
                    int   di = better1 ? oi : code;
                    bool ins2 = (dv < b2v[e]) || (dv == b2v[e] && di < b2i[e]);
                    if (ins2) { b2v[e] = dv; b2i[e] = di; }
                }
        }

        // ---- half boundary: merge wave-local top2 across code columns ----
        if ((nt & 3) == 3) {
            const int h = nt >> 2;
            #pragma unroll
            for (int e = 0; e < 16; ++e) {
                #pragma unroll
                for (int off = 1; off <= 8; off <<= 1) {
                    float o1v = __shfl_xor(b1v[e], off, 64); int o1i = __shfl_xor(b1i[e], off, 64);
                    float o2v = __shfl_xor(b2v[e], off, 64); int o2i = __shfl_xor(b2i[e], off, 64);
                    bool t1 = (o1v < b1v[e]) || (o1v == b1v[e] && o1i < b1i[e]);
                    float dv = t1 ? b1v[e] : o1v; int di = t1 ? b1i[e] : o1i;
                    if (t1) { b1v[e] = o1v; b1i[e] = o1i; }
                    bool t2 = (dv < b2v[e]) || (dv == b2v[e] && di < b2i[e]);
                    if (t2) { b2v[e] = dv; b2i[e] = di; }
                    bool t3 = (o2v < b2v[e]) || (o2v == b2v[e] && o2i < b2i[e]);
                    if (t3) { b2v[e] = o2v; b2i[e] = o2i; }
                }
            }
            if ((lane & 15) == 0) {
                #pragma unroll
                for (int mf = 0; mf < 4; ++mf)
                    #pragma unroll
                    for (int rg = 0; rg < 4; ++rg) {
                        const int rl = mf * 16 + (lane >> 4) * 4 + rg;
                        const int e = mf * 4 + rg;
                        mv[h][wid][rl][0] = b1v[e]; mi[h][wid][rl][0] = b1i[e];
                        mv[h][wid][rl][1] = b2v[e]; mi[h][wid][rl][1] = b2i[e];
                    }
            }
            #pragma unroll
            for (int e = 0; e < 16; ++e) {
                b1v[e] = FLT_MAX; b2v[e] = FLT_MAX;
                b1i[e] = 0x7fffffff; b2i[e] = 0x7fffffff;
            }
        }
    }

    __syncthreads();
    // ---- final merge across the 4 waves, write top-2 per half ----
    if (tid < 128) {
        const int h = tid >> 6, r = tid & 63;
        float v1 = FLT_MAX, v2 = FLT_MAX;
        int i1 = 0x7fffffff, i2 = 0x7fffffff;
        #pragma unroll
        for (int w = 0; w < 4; ++w)
            #pragma unroll
            for (int e2 = 0; e2 < 2; ++e2) {
                float v = mv[h][w][r][e2]; int ii = mi[h][w][r][e2];
                bool t1 = (v < v1) || (v == v1 && ii < i1);
                if (t1) { v2 = v1; i2 = i1; v1 = v; i1 = ii; }
                else {
                    bool t2 = (v < v2) || (v == v2 && ii < i2);
                    if (t2) { v2 = v; i2 = ii; }
                }
            }
        top2[(m0 + r) * 4 + h * 2 + 0] = i1;
        top2[(m0 + r) * 4 + h * 2 + 1] = i2;
    }
}

// ---------------- exact rescore of 4 candidates + epilogue ----------------
// (proven in R3/R4 — unchanged)
__global__ __launch_bounds__(256)
void vq_rescue_kernel(const float* __restrict__ z, const float* __restrict__ emb,
                      const float* __restrict__ zsq_g, const float* __restrict__ esq_g,
                      const int* __restrict__ top2,
                      float* __restrict__ out, float* __restrict__ loss_acc) {
    __shared__ float lred[4];
    const int tid = threadIdx.x;
    const int wid = tid >> 6, lane = tid & 63;
    const int row = blockIdx.x * 4 + wid;
    const int cand = top2[row * 4 + (lane & 3)];
    const float* zr = z + (size_t)row * DIM;
    const float* er = emb + (size_t)cand * DIM;
    float a = 0.f;
    #pragma unroll 8
    for (int d4 = 0; d4 < 64; ++d4) {
        float4 zv = *(const float4*)&zr[4 * d4];
        float4 ev = *(const float4*)&er[4 * d4];
        a = fmaf(zv.x, ev.x, a); a = fmaf(zv.y, ev.y, a);
        a = fmaf(zv.z, ev.z, a); a = fmaf(zv.w, ev.w, a);
    }
    float t = zsq_g[row] + esq_g[cand];
    float dist = t - 2.0f * a;
    int best = cand;
    #pragma unroll
    for (int off = 1; off <= 2; off <<= 1) {
        float ov = __shfl_xor(dist, off, 64);
        int   oi = __shfl_xor(best, off, 64);
        bool tk = (ov < dist) || (ov == dist && oi < best);
        dist = tk ? ov : dist; best = tk ? oi : best;
    }
    float4 q4 = *(const float4*)&emb[(size_t)best * DIM + 4 * lane];
    float4 z4 = *(const float4*)&zr[4 * lane];
    float4 o; float dx, lsum = 0.f;
    dx = q4.x - z4.x; o.x = z4.x + dx; lsum = fmaf(dx, dx, lsum);
    dx = q4.y - z4.y; o.y = z4.y + dx; lsum = fmaf(dx, dx, lsum);
    dx = q4.z - z4.z; o.z = z4.z + dx; lsum = fmaf(dx, dx, lsum);
    dx = q4.w - z4.w; o.w = z4.w + dx; lsum = fmaf(dx, dx, lsum);
    *(float4*)&out[(size_t)row * DIM + 4 * lane] = o;
    #pragma unroll
    for (int off = 32; off >= 1; off >>= 1) lsum += __shfl_xor(lsum, off, 64);
    if (lane == 0) lred[wid] = lsum;
    __syncthreads();
    if (tid == 0) atomicAdd(loss_acc, lred[0] + lred[1] + lred[2] + lred[3]);
    if (lane == 0) out[(size_t)N_ROWS * DIM + 1 + row] = (float)best;
}

// =================== legacy R2 path (fallback if ws too small) ===========
#define MT 128
#define KT 256
#define DC 16
#define BLOCK 256
#define ZSTR (MT + 4)
#define ESTR (KT + 4)
#define NSTAGES ((DIM / DC) * (K_CODES / KT))

#define LOHALF(v) __builtin_shufflevector(v, v, 0, 1)
#define HIHALF(v) __builtin_shufflevector(v, v, 2, 3)
#define PK_FMA_LO(acc, ap, bp) \
    asm("v_pk_fma_f32 %0, %1, %2, %0 op_sel:[0,0,0] op_sel_hi:[0,1,1]" \
        : "+v"(acc) : "v"(ap), "v"(bp))
#define PK_FMA_HI(acc, ap, bp) \
    asm("v_pk_fma_f32 %0, %1, %2, %0 op_sel:[1,0,0] op_sel_hi:[1,1,1]" \
        : "+v"(acc) : "v"(ap), "v"(bp))

__global__ __launch_bounds__(BLOCK, 1)
void vq_main_kernel(const float* __restrict__ z,
                    const float* __restrict__ emb,
                    const float* __restrict__ esq,
                    float* __restrict__ out,
                    float* __restrict__ loss_acc) {
    __shared__ float zS[2][DC][ZSTR];
    __shared__ float eT[2][DC][ESTR];
    __shared__ float zsq_s[MT];
    __shared__ int   best_s[MT];
    __shared__ float lred[4];

    const int tid = threadIdx.x;
    const int m0  = blockIdx.x * MT;
    const int rg  = tid >> 5;
    const int cg  = tid & 31;
    const int esr = tid >> 2;
    const int esf = tid & 3;
    const int zr  = tid >> 1;
    const int zh  = tid & 1;

    {
        const float* zp = &z[(size_t)(m0 + zr) * DIM + zh * 64];
        float sA = 0.f, sB = 0.f;
        #pragma unroll
        for (int d4 = 0; d4 < 16; ++d4) {
            float4 v = *(const float4*)&zp[d4 * 4];
            sA += v.x * v.x; sA += v.y * v.y; sA += v.z * v.z; sA += v.w * v.w;
        }
        #pragma unroll
        for (int d4 = 0; d4 < 16; ++d4) {
            float4 v = *(const float4*)&zp[128 + d4 * 4];
            sB += v.x * v.x; sB += v.y * v.y; sB += v.z * v.z; sB += v.w * v.w;
        }
        float s = sA + sB;
        s += __shfl_down(s, 1, 64);
        if (zh == 0) zsq_s[zr] = s;
    }
    {
        const float* zp = &z[(size_t)(m0 + zr) * DIM + 8 * zh];
        float4 za = *(const float4*)&zp[0];
        float4 zb = *(const float4*)&zp[4];
        zS[0][8 * zh + 0][zr] = za.x; zS[0][8 * zh + 1][zr] = za.y;
        zS[0][8 * zh + 2][zr] = za.z; zS[0][8 * zh + 3][zr] = za.w;
        zS[0][8 * zh + 4][zr] = zb.x; zS[0][8 * zh + 5][zr] = zb.y;
        zS[0][8 * zh + 6][zr] = zb.z; zS[0][8 * zh + 7][zr] = zb.w;
        #pragma unroll
        for (int cb = 0; cb < 4; ++cb) {
            int c = esr + cb * 64;
            float4 ev = *(const float4*)&emb[(size_t)c * DIM + 4 * esf];
            eT[0][4 * esf + 0][c] = ev.x; eT[0][4 * esf + 1][c] = ev.y;
            eT[0][4 * esf + 2][c] = ev.z; eT[0][4 * esf + 3][c] = ev.w;
        }
    }
    __syncthreads();

    float bestv[16];
    int   besti[16];
    #pragma unroll
    for (int j = 0; j < 16; ++j) { bestv[j] = FLT_MAX; besti[j] = 0; }

    f32x2 acc2[16][4];

    for (int s = 0; s < NSTAGES; ++s) {
        const int p     = s & 1;
        const int kt    = (s >> 4) * KT;
        const int dcIdx = s & 15;

        if (dcIdx == 0) {
            #pragma unroll
            for (int j = 0; j < 16; ++j)
                #pragma unroll
                for (int i2 = 0; i2 < 4; ++i2) acc2[j][i2] = (f32x2){0.f, 0.f};
        }

        const int sn  = (s + 1 < NSTAGES) ? s + 1 : s;
        const int nkt = (sn >> 4) * KT;
        const int ndc = (sn & 15) * DC;
        float4 zn0 = *(const float4*)&z[(size_t)(m0 + zr) * DIM + ndc + 8 * zh];
        float4 zn1 = *(const float4*)&z[(size_t)(m0 + zr) * DIM + ndc + 8 * zh + 4];
        float4 en0 = *(const float4*)&emb[(size_t)(nkt + esr +   0) * DIM + ndc + 4 * esf];
        float4 en1 = *(const float4*)&emb[(size_t)(nkt + esr +  64) * DIM + ndc + 4 * esf];
        float4 en2 = *(const float4*)&emb[(size_t)(nkt + esr + 128) * DIM + ndc + 4 * esf];
        float4 en3 = *(const float4*)&emb[(size_t)(nkt + esr + 192) * DIM + ndc + 4 * esf];

        #pragma unroll
        for (int d = 0; d < DC; ++d) {
            f32x4 a0 = *(const f32x4*)&zS[p][d][16 * rg];
            f32x4 a1 = *(const f32x4*)&zS[p][d][16 * rg + 4];
            f32x4 a2 = *(const f32x4*)&zS[p][d][16 * rg + 8];
            f32x4 a3 = *(const f32x4*)&zS[p][d][16 * rg + 12];
            f32x4 b0 = *(const f32x4*)&eT[p][d][4 * cg];
            f32x4 b1 = *(const f32x4*)&eT[p][d][128 + 4 * cg];
            f32x2 ap[8] = { LOHALF(a0), HIHALF(a0), LOHALF(a1), HIHALF(a1),
                            LOHALF(a2), HIHALF(a2), LOHALF(a3), HIHALF(a3) };
            f32x2 bp[4] = { LOHALF(b0), HIHALF(b0), LOHALF(b1), HIHALF(b1) };
            #pragma unroll
            for (int jp = 0; jp < 8; ++jp) {
                #pragma unroll
                for (int i2 = 0; i2 < 4; ++i2) {
                    PK_FMA_LO(acc2[2 * jp][i2],     ap[jp], bp[i2]);
                    PK_FMA_HI(acc2[2 * jp + 1][i2], ap[jp], bp[i2]);
                }
            }
        }
        {
            const int q = p ^ 1;
            zS[q][8 * zh + 0][zr] = zn0.x; zS[q][8 * zh + 1][zr] = zn0.y;
            zS[q][8 * zh + 2][zr] = zn0.z; zS[q][8 * zh + 3][zr] = zn0.w;
            zS[q][8 * zh + 4][zr] = zn1.x; zS[q][8 * zh + 5][zr] = zn1.y;
            zS[q][8 * zh + 6][zr] = zn1.z; zS[q][8 * zh + 7][zr] = zn1.w;
            eT[q][4 * esf + 0][esr      ] = en0.x; eT[q][4 * esf + 1][esr      ] = en0.y;
            eT[q][4 * esf + 2][esr      ] = en0.z; eT[q][4 * esf + 3][esr      ] = en0.w;
            eT[q][4 * esf + 0][esr +  64] = en1.x; eT[q][4 * esf + 1][esr +  64] = en1.y;
            eT[q][4 * esf + 2][esr +  64] = en1.z; eT[q][4 * esf + 3][esr +  64] = en1.w;
            eT[q][4 * esf + 0][esr + 128] = en2.x; eT[q][4 * esf + 1][esr + 128] = en2.y;
            eT[q][4 * esf + 2][esr + 128] = en2.z; eT[q][4 * esf + 3][esr + 128] = en2.w;
            eT[q][4 * esf + 0][esr + 192] = en3.x; eT[q][4 * esf + 1][esr + 192] = en3.y;
            eT[q][4 * esf + 2][esr + 192] = en3.z; eT[q][4 * esf + 3][esr + 192] = en3.w;
        }
        if (dcIdx == 15) {
            float4 e0 = *(const float4*)&esq[kt + 4 * cg];
            float4 e1 = *(const float4*)&esq[kt + 128 + 4 * cg];
            float es[8] = {e0.x, e0.y, e0.z, e0.w, e1.x, e1.y, e1.z, e1.w};
            #pragma unroll
            for (int j = 0; j < 16; ++j) {
                float zs = zsq_s[16 * rg + j];
                #pragma unroll
                for (int i = 0; i < 8; ++i) {
                    float aij  = acc2[j][i >> 1][i & 1];
                    float t    = zs + es[i];
                    float dist = t - 2.0f * aij;
                    int idx = (i < 4) ? (kt + 4 * cg + i) : (kt + 128 + 4 * cg + (i - 4));
                    bool better = (dist < bestv[j]);
                    bestv[j] = better ? dist : bestv[j];
                    besti[j] = better ? idx  : besti[j];
                }
            }
        }
        __syncthreads();
    }

    #pragma unroll
    for (int off = 16; off >= 1; off >>= 1) {
        #pragma unroll
        for (int j = 0; j < 16; ++j) {
            float ov = __shfl_xor(bestv[j], off, 64);
            int   oi = __shfl_xor(besti[j], off, 64);
            bool take = (ov < bestv[j]) || (ov == bestv[j] && oi < besti[j]);
            bestv[j] = take ? ov : bestv[j];
            besti[j] = take ? oi : besti[j];
        }
    }
    if (cg == 0) {
        #pragma unroll
        for (int j = 0; j < 16; ++j) best_s[16 * rg + j] = besti[j];
    }
    __syncthreads();

    float lsum = 0.f;
    const int d4 = tid & 63;
    for (int it = 0; it < 32; ++it) {
        int r  = (tid >> 6) + it * 4;
        int bk = best_s[r];
        float4 q4 = *(const float4*)&emb[(size_t)bk * DIM + 4 * d4];
        float4 z4 = *(const float4*)&z[(size_t)(m0 + r) * DIM + 4 * d4];
        float4 o;
        float dx;
        dx = q4.x - z4.x; o.x = z4.x + dx; lsum = fmaf(dx, dx, lsum);
        dx = q4.y - z4.y; o.y = z4.y + dx; lsum = fmaf(dx, dx, lsum);
        dx = q4.z - z4.z; o.z = z4.z + dx; lsum = fmaf(dx, dx, lsum);
        dx = q4.w - z4.w; o.w = z4.w + dx; lsum = fmaf(dx, dx, lsum);
        *(float4*)&out[(size_t)(m0 + r) * DIM + 4 * d4] = o;
    }
    #pragma unroll
    for (int off = 32; off >= 1; off >>= 1) lsum += __shfl_xor(lsum, off, 64);
    if ((tid & 63) == 0) lred[tid >> 6] = lsum;
    __syncthreads();
    if (tid == 0) {
        float bs = lred[0] + lred[1] + lred[2] + lred[3];
        atomicAdd(loss_acc, bs);
    }
    if (tid < MT) out[(size_t)N_ROWS * DIM + 1 + m0 + tid] = (float)best_s[tid];
}

// ---------------- finalize: vq_loss = 1.25 * mean ----------------
__global__ void vq_finalize_kernel(const float* __restrict__ loss_acc,
                                   float* __restrict__ out) {
    double s = (double)loss_acc[0];
    out[(size_t)N_ROWS * DIM] = (float)(s * 1.25 / ((double)N_ROWS * (double)DIM));
}

extern "C" void kernel_launch(void* const* d_in, const int* in_sizes, int n_in,
                              void* d_out, int out_size, void* d_ws, size_t ws_size,
                              hipStream_t stream) {
    (void)in_sizes; (void)n_in; (void)out_size;
    const float* z   = (const float*)d_in[0];
    const float* emb = (const float*)d_in[1];
    float* out = (float*)d_out;
    char* wsb = (char*)d_ws;
    float* loss_acc = (float*)wsb;              // @0
    float* esq      = (float*)(wsb + 1024);     // 2048 f

    hipMemsetAsync(d_ws, 0, sizeof(float), stream);
    vq_esq_kernel<<<K_CODES / 4, 256, 0, stream>>>(emb, esq);

    const size_t NEED = (size_t)72 << 20;       // Zh/Zm end at 72 MiB
    if (ws_size >= NEED) {
        float* zsq_g = (float*)(wsb + 16384);              // 65536 f
        int*   top2  = (int*)(wsb + ((size_t)1 << 19));    // 65536*4 int
        unsigned short* Eh = (unsigned short*)(wsb + ((size_t)2 << 20));
        unsigned short* Em = (unsigned short*)(wsb + ((size_t)3 << 20));
        unsigned short* Zh = (unsigned short*)(wsb + ((size_t)8 << 20));
        unsigned short* Zm = (unsigned short*)(wsb + ((size_t)40 << 20));
        vq_zsq_kernel<<<N_ROWS / 128, 256, 0, stream>>>(z, zsq_g);
        vq_split2_kernel<<<(N_ROWS * DIM) / 1024, 256, 0, stream>>>(z, Zh, Zm);
        vq_split2_kernel<<<(K_CODES * DIM) / 1024, 256, 0, stream>>>(emb, Eh, Em);
        vq_gemm_kernel<<<N_ROWS / 64, 256, 0, stream>>>(Zh, Zm, Eh, Em,
                                                        zsq_g, esq, top2);
        vq_rescue_kernel<<<N_ROWS / 4, 256, 0, stream>>>(z, emb, zsq_g, esq, top2,
                                                         out, loss_acc);
    } else {
        vq_main_kernel<<<N_ROWS / MT, BLOCK, 0, stream>>>(z, emb, esq, out, loss_acc);
    }
    vq_finalize_kernel<<<1, 1, 0, stream>>>(loss_acc, out);
}